// Round 3
// baseline (273.359 us; speedup 1.0000x reference)
//
#include <hip/hip_runtime.h>
#include <math.h>

#define L_SEQ 8192
#define H_DIM 1024
#define N_DIM 1024
#define K2    2048          // packed K = 2*H = 2*N
#define KSEG  1024          // split-K segment for GEMM2
#define NCHUNK 64
#define CHUNK 128

typedef unsigned short u16;
typedef __attribute__((ext_vector_type(8))) __bf16 bf16x8;
typedef __attribute__((ext_vector_type(4))) float  f32x4;

__device__ __forceinline__ u16 f2bf(float x) {
    unsigned int u = __float_as_uint(x);
    u = (u + 0x7fffu + ((u >> 16) & 1u)) >> 16;   // RNE
    return (u16)u;
}
__device__ __forceinline__ float bf2f(u16 h) {
    return __uint_as_float(((unsigned int)h) << 16);
}

__device__ __forceinline__ void gload_lds16(const void* g, void* s) {
    __builtin_amdgcn_global_load_lds(
        (const __attribute__((address_space(1))) unsigned int*)g,
        (__attribute__((address_space(3))) unsigned int*)s, 16, 0, 0);
}

// ---------------------------------------------------------------------------
// Lambda = exp(-exp(nu_log) + i*exp(theta_log))
// ---------------------------------------------------------------------------
__global__ void lru_lambda(const float* __restrict__ nu_log,
                           const float* __restrict__ theta_log,
                           float* __restrict__ Lr, float* __restrict__ Li) {
    int n = blockIdx.x * 256 + threadIdx.x;
    float nu  = expf(nu_log[n]);
    float th  = expf(theta_log[n]);
    float mag = expf(-nu);
    Lr[n] = mag * cosf(th);
    Li[n] = mag * sinf(th);
}

// ---------------------------------------------------------------------------
// Pack u -> A' bf16 [L][2H]: cols [0,1024)=u_r, [1024,2048)=u_i
// ---------------------------------------------------------------------------
__global__ void pack_u(const float* __restrict__ R, const float* __restrict__ I,
                       u16* __restrict__ A) {
    size_t t = (size_t)blockIdx.x * 256 + threadIdx.x;
    size_t base = t * 4;                      // over L*H
    int lrow = (int)(base >> 10);
    int h    = (int)(base & 1023);
    float4 r  = *reinterpret_cast<const float4*>(R + base);
    float4 im = *reinterpret_cast<const float4*>(I + base);
    u16* p0 = A + ((size_t)lrow << 11) + h;
    *reinterpret_cast<ushort4*>(p0) =
        make_ushort4(f2bf(r.x), f2bf(r.y), f2bf(r.z), f2bf(r.w));
    *reinterpret_cast<ushort4*>(p0 + 1024) =
        make_ushort4(f2bf(im.x), f2bf(im.y), f2bf(im.z), f2bf(im.w));
}

// ---------------------------------------------------------------------------
// B_norm pack -> Bp bf16 [2N][2H]:
//   row n      : [ bnr | -bni ]   (produces Bu_r in output col n)
//   row 1024+n : [ bni |  bnr ]   (produces Bu_i in output col 1024+n)
// ---------------------------------------------------------------------------
__global__ void bnorm_pack(const float* __restrict__ Br, const float* __restrict__ Bi,
                           const float* __restrict__ G, u16* __restrict__ Bp) {
    size_t t = (size_t)blockIdx.x * 256 + threadIdx.x;
    size_t base = t * 4;                      // over N*H
    int n = (int)(base >> 10);
    int h = (int)(base & 1023);
    float g = G[n];
    float sg, cg;
    sincosf(g, &sg, &cg);
    float4 br = *reinterpret_cast<const float4*>(Br + base);
    float4 bi = *reinterpret_cast<const float4*>(Bi + base);
    float nr0 = br.x * cg - bi.x * sg, ni0 = br.x * sg + bi.x * cg;
    float nr1 = br.y * cg - bi.y * sg, ni1 = br.y * sg + bi.y * cg;
    float nr2 = br.z * cg - bi.z * sg, ni2 = br.z * sg + bi.z * cg;
    float nr3 = br.w * cg - bi.w * sg, ni3 = br.w * sg + bi.w * cg;
    u16* row0 = Bp + (size_t)n * K2;
    u16* row1 = Bp + (size_t)(N_DIM + n) * K2;
    *reinterpret_cast<ushort4*>(row0 + h) =
        make_ushort4(f2bf(nr0), f2bf(nr1), f2bf(nr2), f2bf(nr3));
    *reinterpret_cast<ushort4*>(row0 + 1024 + h) =
        make_ushort4(f2bf(-ni0), f2bf(-ni1), f2bf(-ni2), f2bf(-ni3));
    *reinterpret_cast<ushort4*>(row1 + h) =
        make_ushort4(f2bf(ni0), f2bf(ni1), f2bf(ni2), f2bf(ni3));
    *reinterpret_cast<ushort4*>(row1 + 1024 + h) =
        make_ushort4(f2bf(nr0), f2bf(nr1), f2bf(nr2), f2bf(nr3));
}

// ---------------------------------------------------------------------------
// C pack -> Cp bf16 [H][2N]: row h = [ C_r[h][:] | -C_i[h][:] ]
// ---------------------------------------------------------------------------
__global__ void pack_C(const float* __restrict__ Cr, const float* __restrict__ Ci,
                       u16* __restrict__ Cp) {
    size_t t = (size_t)blockIdx.x * 256 + threadIdx.x;
    size_t base = t * 4;                      // over H*N
    int h = (int)(base >> 10);
    int n = (int)(base & 1023);
    float4 cr = *reinterpret_cast<const float4*>(Cr + base);
    float4 ci = *reinterpret_cast<const float4*>(Ci + base);
    u16* row = Cp + (size_t)h * K2;
    *reinterpret_cast<ushort4*>(row + n) =
        make_ushort4(f2bf(cr.x), f2bf(cr.y), f2bf(cr.z), f2bf(cr.w));
    *reinterpret_cast<ushort4*>(row + 1024 + n) =
        make_ushort4(f2bf(-ci.x), f2bf(-ci.y), f2bf(-ci.z), f2bf(-ci.w));
}

// ---------------------------------------------------------------------------
// bf16 MFMA GEMM, m97 structure: 128x128 tile, BK=32, 4 waves (2x2),
// 16x16x32 MFMA, global_load_lds width-16.
// LDS swizzle: 64-byte rows, 4x 16B slots; phys_slot = log_slot ^ ((row>>1)&3)
// -> each 16-lane ds_read_b128 group lands exactly 2 lanes/bank-quad (free).
// Applied BOTH sides (rule #21): inverse-swizzled global source (linear LDS
// dest for global_load_lds) + swizzled ds_read address.
// XCD-aware bijective block swizzle (grid divisible by 8).
// A: [M][lda] bf16 row-major, B: [Nout][lda] bf16 row-major -> Out = A*B^T.
// EPI==0: store bf16 to OutB.
// EPI==1: OutF = acc + Dv[col]*Ur[row,col]  (full-K GEMM2, unused now)
// EPI==2: split-K: bz==0 -> P0 = acc ; bz==1 -> OutF = acc + Dv[col]*Ur.
// ---------------------------------------------------------------------------
template <int EPI>
__global__ __launch_bounds__(256) void mfma_gemm(
    const u16* __restrict__ A, const u16* __restrict__ B, int Klen, int lda,
    u16* __restrict__ OutB, float* __restrict__ OutF, int ldo,
    const float* __restrict__ Dv, const float* __restrict__ Ur,
    float* __restrict__ P0) {
    __shared__ u16 Abuf[128 * 32];
    __shared__ u16 Bbuf[128 * 32];
    const int tid = threadIdx.x;
    const int l   = tid & 63;
    const int w   = tid >> 6;       // wave 0..3
    const int wm  = w >> 1, wn = w & 1;

    // XCD-aware bijective swizzle over the full linear grid
    const int nx = gridDim.x, ny = gridDim.y;
    int lin = blockIdx.x + nx * (blockIdx.y + ny * blockIdx.z);
    int nwg = nx * ny * gridDim.z;
    int id  = (lin & 7) * (nwg >> 3) + (lin >> 3);
    int bxi = id % nx;
    int rem = id / nx;
    int byi = rem % ny;
    int bz  = rem / ny;

    const long bm = (long)bxi * 128;
    const long bn = (long)byi * 128;

    f32x4 acc[4][4];
#pragma unroll
    for (int i = 0; i < 4; ++i)
#pragma unroll
        for (int j = 0; j < 4; ++j) acc[i][j] = (f32x4){0.f, 0.f, 0.f, 0.f};

    // split-K offset (element offset into each row)
    const u16* Ae = (EPI == 2) ? (A + (size_t)bz * KSEG) : A;
    const u16* Be = (EPI == 2) ? (B + (size_t)bz * KSEG) : B;

    // Staging: wave w + instr p fill LDS chunk (p*4+w) of 1KB.
    // lane l -> row 16*chunk + (l>>2), phys slot (l&3).
    // source logical slot = (l&3) ^ ((row>>1)&3), row-in-chunk = l>>2.
    const int srow = l >> 2;
    const int scb  = (((l & 3) ^ ((l >> 3) & 3)) << 4);
    const char* Ag0 = (const char*)(Ae + (size_t)(bm + w * 16 + srow) * lda) + scb;
    const char* Ag1 = (const char*)(Ae + (size_t)(bm + 64 + w * 16 + srow) * lda) + scb;
    const char* Bg0 = (const char*)(Be + (size_t)(bn + w * 16 + srow) * lda) + scb;
    const char* Bg1 = (const char*)(Be + (size_t)(bn + 64 + w * 16 + srow) * lda) + scb;
    u16* lA0 = Abuf + w * 512;
    u16* lA1 = Abuf + (4 + w) * 512;
    u16* lB0 = Bbuf + w * 512;
    u16* lB1 = Bbuf + (4 + w) * 512;

    // Fragment reads: lane l reads rows (wq*64 + f*16 + (l&15)), logical slot
    // l>>4; physical slot = (l>>4) ^ ((row>>1)&3), (row>>1)&3 == (l>>1)&3.
    const int fcb = ((((l >> 4) ^ (l >> 1)) & 3) << 4);
    const int ra  = wm * 64 + (l & 15);
    const int rb  = wn * 64 + (l & 15);

    for (int k0 = 0; k0 < Klen; k0 += 32) {
        gload_lds16(Ag0 + (size_t)2 * k0, lA0);
        gload_lds16(Ag1 + (size_t)2 * k0, lA1);
        gload_lds16(Bg0 + (size_t)2 * k0, lB0);
        gload_lds16(Bg1 + (size_t)2 * k0, lB1);
        __syncthreads();                       // drains vmcnt: tiles resident
        bf16x8 af[4], bg[4];
#pragma unroll
        for (int mi = 0; mi < 4; ++mi)
            af[mi] = *reinterpret_cast<const bf16x8*>(
                (const char*)Abuf + (ra + mi * 16) * 64 + fcb);
#pragma unroll
        for (int ni = 0; ni < 4; ++ni)
            bg[ni] = *reinterpret_cast<const bf16x8*>(
                (const char*)Bbuf + (rb + ni * 16) * 64 + fcb);
#pragma unroll
        for (int mi = 0; mi < 4; ++mi)
#pragma unroll
            for (int ni = 0; ni < 4; ++ni)
                acc[mi][ni] = __builtin_amdgcn_mfma_f32_16x16x32_bf16(
                    af[mi], bg[ni], acc[mi][ni], 0, 0, 0);
        __syncthreads();                       // all reads done before restage
    }

    // C/D layout (m89-verified): col = lane&15, row = (lane>>4)*4 + reg
#pragma unroll
    for (int mi = 0; mi < 4; ++mi) {
        const long row0 = bm + wm * 64 + mi * 16 + ((l >> 4) << 2);
#pragma unroll
        for (int ni = 0; ni < 4; ++ni) {
            const long col = bn + wn * 64 + ni * 16 + (l & 15);
            if (EPI == 0) {
#pragma unroll
                for (int r = 0; r < 4; ++r)
                    OutB[(size_t)(row0 + r) * ldo + col] = f2bf(acc[mi][ni][r]);
            } else if (EPI == 1) {
                const float d = Dv[col];
#pragma unroll
                for (int r = 0; r < 4; ++r) {
                    size_t o = (size_t)(row0 + r) * ldo + col;
                    OutF[o] = acc[mi][ni][r] + d * Ur[o];
                }
            } else {
                if (bz == 0) {
#pragma unroll
                    for (int r = 0; r < 4; ++r) {
                        size_t o = (size_t)(row0 + r) * ldo + col;
                        P0[o] = acc[mi][ni][r];
                    }
                } else {
                    const float d = Dv[col];
#pragma unroll
                    for (int r = 0; r < 4; ++r) {
                        size_t o = (size_t)(row0 + r) * ldo + col;
                        OutF[o] = acc[mi][ni][r] + d * Ur[o];
                    }
                }
            }
        }
    }
}

// ---------------------------------------------------------------------------
// Split-K combine: y += P0   (float4)
// ---------------------------------------------------------------------------
__global__ void combine_add(float* __restrict__ y, const float* __restrict__ P0) {
    size_t i = ((size_t)blockIdx.x * 256 + threadIdx.x) * 4;
    float4 a = *reinterpret_cast<const float4*>(y + i);
    float4 b = *reinterpret_cast<const float4*>(P0 + i);
    a.x += b.x; a.y += b.y; a.z += b.z; a.w += b.w;
    *reinterpret_cast<float4*>(y + i) = a;
}

// ---------------------------------------------------------------------------
// Scan pass A: per-(chunk, channel) local scan in fp32 state over bf16 X,
// in-place; emits Lambda^CHUNK and the local final state per chunk (fp32).
// X layout: [L][2048], col n = real, col 1024+n = imag.
// ---------------------------------------------------------------------------
__global__ void scan_local(u16* __restrict__ X,
                           const float* __restrict__ Lr, const float* __restrict__ Li,
                           float* __restrict__ Acr, float* __restrict__ Aci,
                           float* __restrict__ bcr, float* __restrict__ bci) {
    int n = blockIdx.y * 256 + threadIdx.x;   // 0..1023
    int c = blockIdx.x;
    float lr = Lr[n], li = Li[n];
    float sr = 0.f, si = 0.f, pr = 1.f, pi = 0.f;
    size_t base = (size_t)c * CHUNK * K2 + n;
    for (int j = 0; j < CHUNK; ++j) {
        size_t idx = base + (size_t)j * K2;
        float br = bf2f(X[idx]), bi = bf2f(X[idx + 1024]);
        float nr = lr * sr - li * si + br;
        float ni = lr * si + li * sr + bi;
        sr = nr; si = ni;
        X[idx] = f2bf(sr); X[idx + 1024] = f2bf(si);
        float qr = lr * pr - li * pi;
        float qi = lr * pi + li * pr;
        pr = qr; pi = qi;
    }
    Acr[c * N_DIM + n] = pr; Aci[c * N_DIM + n] = pi;
    bcr[c * N_DIM + n] = sr; bci[c * N_DIM + n] = si;
}

// ---------------------------------------------------------------------------
// Scan pass B: sequential scan over NCHUNK chunk summaries (fp32).
// ---------------------------------------------------------------------------
__global__ void scan_carry(const float* __restrict__ Acr, const float* __restrict__ Aci,
                           const float* __restrict__ bcr, const float* __restrict__ bci,
                           float* __restrict__ car, float* __restrict__ cai) {
    int n = blockIdx.x * 256 + threadIdx.x;
    float sr = 0.f, si = 0.f;
    for (int c = 0; c < NCHUNK; ++c) {
        car[c * N_DIM + n] = sr; cai[c * N_DIM + n] = si;
        float ar = Acr[c * N_DIM + n], ai = Aci[c * N_DIM + n];
        float nr = ar * sr - ai * si + bcr[c * N_DIM + n];
        float ni = ar * si + ai * sr + bci[c * N_DIM + n];
        sr = nr; si = ni;
    }
}

// ---------------------------------------------------------------------------
// Scan pass C: X[c*CHUNK+j] += Lambda^(j+1) * carry_in[c]   (bf16 RMW)
// ---------------------------------------------------------------------------
__global__ void scan_fix(u16* __restrict__ X,
                         const float* __restrict__ Lr, const float* __restrict__ Li,
                         const float* __restrict__ car, const float* __restrict__ cai) {
    int n = blockIdx.y * 256 + threadIdx.x;
    int c = blockIdx.x + 1;
    float lr = Lr[n], li = Li[n];
    float cr = car[c * N_DIM + n], ci = cai[c * N_DIM + n];
    float pr = lr * cr - li * ci;
    float pi = lr * ci + li * cr;
    size_t base = (size_t)c * CHUNK * K2 + n;
    for (int j = 0; j < CHUNK; ++j) {
        size_t idx = base + (size_t)j * K2;
        X[idx]        = f2bf(bf2f(X[idx]) + pr);
        X[idx + 1024] = f2bf(bf2f(X[idx + 1024]) + pi);
        float qr = lr * pr - li * pi;
        float qi = lr * pi + li * pr;
        pr = qr; pi = qi;
    }
}

// ---------------------------------------------------------------------------
// Launch
// ---------------------------------------------------------------------------
extern "C" void kernel_launch(void* const* d_in, const int* in_sizes, int n_in,
                              void* d_out, int out_size, void* d_ws, size_t ws_size,
                              hipStream_t stream) {
    (void)in_sizes; (void)n_in; (void)out_size; (void)ws_size;
    const float* input_real = (const float*)d_in[0];
    const float* input_imag = (const float*)d_in[1];
    const float* nu_log     = (const float*)d_in[2];
    const float* theta_log  = (const float*)d_in[3];
    const float* B_real     = (const float*)d_in[4];
    const float* B_imag     = (const float*)d_in[5];
    const float* C_real     = (const float*)d_in[6];
    const float* C_imag     = (const float*)d_in[7];
    const float* D          = (const float*)d_in[8];
    const float* gamma_log  = (const float*)d_in[9];
    float* y = (float*)d_out;

    // Workspace layout (bytes):
    // [0, 4K)            Lr          [4K, 8K)   Li
    // [8K, 8K+1.5M)      Acr/Aci/bcr/bci/car/cai (6 x 256KB)
    // [2M, 34M)          A' bf16 [8192][2048]   (dead after gemm1)
    //   [2M, 6M)           Cp aliases A' head   (alive after pack_C)
    //   [6M, 38M)          P0 fp32 [8192][1024] (split-K partial; aliases
    //                      A' tail + Bp head, both dead after gemm1)
    // [34M, 42M)         Bp bf16 [2048][2048]   (dead after gemm1)
    // [42M, 74M)         X  bf16 [8192][2048]   (Bu -> x in place)
    char* ws = (char*)d_ws;
    float* Lr  = (float*)(ws);
    float* Li  = (float*)(ws + (4 << 10));
    float* Acr = (float*)(ws + (8 << 10));
    float* Aci = Acr + NCHUNK * N_DIM;
    float* bcr = Aci + NCHUNK * N_DIM;
    float* bci = bcr + NCHUNK * N_DIM;
    float* car = bci + NCHUNK * N_DIM;
    float* cai = car + NCHUNK * N_DIM;
    u16* Ap   = (u16*)(ws + ((size_t)2 << 20));
    u16* Cp   = Ap;                                 // alias: used only after gemm1
    float* P0 = (float*)(ws + ((size_t)6 << 20));   // alias: used only after gemm1
    u16* Bp   = (u16*)(ws + ((size_t)34 << 20));
    u16* X    = (u16*)(ws + ((size_t)42 << 20));

    lru_lambda<<<N_DIM / 256, 256, 0, stream>>>(nu_log, theta_log, Lr, Li);
    pack_u<<<(L_SEQ * H_DIM / 4) / 256, 256, 0, stream>>>(input_real, input_imag, Ap);
    bnorm_pack<<<(N_DIM * H_DIM / 4) / 256, 256, 0, stream>>>(B_real, B_imag, gamma_log, Bp);
    mfma_gemm<0><<<dim3(L_SEQ / 128, K2 / 128), 256, 0, stream>>>(
        Ap, Bp, K2, K2, X, nullptr, K2, nullptr, nullptr, nullptr);
    scan_local<<<dim3(NCHUNK, N_DIM / 256), 256, 0, stream>>>(X, Lr, Li, Acr, Aci, bcr, bci);
    scan_carry<<<N_DIM / 256, 256, 0, stream>>>(Acr, Aci, bcr, bci, car, cai);
    scan_fix<<<dim3(NCHUNK - 1, N_DIM / 256), 256, 0, stream>>>(X, Lr, Li, car, cai);
    pack_C<<<(H_DIM * N_DIM / 4) / 256, 256, 0, stream>>>(C_real, C_imag, Cp);
    // GEMM2 split-K x2: bz=0 -> P0 (plain), bz=1 -> y (+ D*u_r epilogue)
    mfma_gemm<2><<<dim3(L_SEQ / 128, H_DIM / 128, 2), 256, 0, stream>>>(
        X, Cp, KSEG, K2, nullptr, y, H_DIM, D, input_real, P0);
    combine_add<<<(L_SEQ * H_DIM / 4) / 256, 256, 0, stream>>>(y, P0);
}

// Round 4
// 207.911 us; speedup vs baseline: 1.3148x; 1.3148x over previous
//
#include <hip/hip_runtime.h>
#include <math.h>

#define L_SEQ 8192
#define H_DIM 1024
#define N_DIM 1024
#define K2    2048          // packed K = 2*H = 2*N
#define KSEG  1024          // split-K segment for GEMM2
#define NCHUNK 64
#define CHUNK 128

typedef unsigned short u16;
typedef __attribute__((ext_vector_type(8))) __bf16 bf16x8;
typedef __attribute__((ext_vector_type(4))) float  f32x4;

__device__ __forceinline__ u16 f2bf(float x) {
    unsigned int u = __float_as_uint(x);
    u = (u + 0x7fffu + ((u >> 16) & 1u)) >> 16;   // RNE
    return (u16)u;
}
__device__ __forceinline__ float bf2f(u16 h) {
    return __uint_as_float(((unsigned int)h) << 16);
}

__device__ __forceinline__ void gload_lds16(const void* g, void* s) {
    __builtin_amdgcn_global_load_lds(
        (const __attribute__((address_space(1))) unsigned int*)g,
        (__attribute__((address_space(3))) unsigned int*)s, 16, 0, 0);
}

// ---------------------------------------------------------------------------
// Lambda = exp(-exp(nu_log) + i*exp(theta_log))
// ---------------------------------------------------------------------------
__global__ void lru_lambda(const float* __restrict__ nu_log,
                           const float* __restrict__ theta_log,
                           float* __restrict__ Lr, float* __restrict__ Li) {
    int n = blockIdx.x * 256 + threadIdx.x;
    float nu  = expf(nu_log[n]);
    float th  = expf(theta_log[n]);
    float mag = expf(-nu);
    Lr[n] = mag * cosf(th);
    Li[n] = mag * sinf(th);
}

// ---------------------------------------------------------------------------
// Pack u -> A' bf16 [L][2H]: cols [0,1024)=u_r, [1024,2048)=u_i
// ---------------------------------------------------------------------------
__global__ void pack_u(const float* __restrict__ R, const float* __restrict__ I,
                       u16* __restrict__ A) {
    size_t t = (size_t)blockIdx.x * 256 + threadIdx.x;
    size_t base = t * 4;                      // over L*H
    int lrow = (int)(base >> 10);
    int h    = (int)(base & 1023);
    float4 r  = *reinterpret_cast<const float4*>(R + base);
    float4 im = *reinterpret_cast<const float4*>(I + base);
    u16* p0 = A + ((size_t)lrow << 11) + h;
    *reinterpret_cast<ushort4*>(p0) =
        make_ushort4(f2bf(r.x), f2bf(r.y), f2bf(r.z), f2bf(r.w));
    *reinterpret_cast<ushort4*>(p0 + 1024) =
        make_ushort4(f2bf(im.x), f2bf(im.y), f2bf(im.z), f2bf(im.w));
}

// ---------------------------------------------------------------------------
// B_norm pack -> Bp bf16 [2N][2H]
// ---------------------------------------------------------------------------
__global__ void bnorm_pack(const float* __restrict__ Br, const float* __restrict__ Bi,
                           const float* __restrict__ G, u16* __restrict__ Bp) {
    size_t t = (size_t)blockIdx.x * 256 + threadIdx.x;
    size_t base = t * 4;                      // over N*H
    int n = (int)(base >> 10);
    int h = (int)(base & 1023);
    float g = G[n];
    float sg, cg;
    sincosf(g, &sg, &cg);
    float4 br = *reinterpret_cast<const float4*>(Br + base);
    float4 bi = *reinterpret_cast<const float4*>(Bi + base);
    float nr0 = br.x * cg - bi.x * sg, ni0 = br.x * sg + bi.x * cg;
    float nr1 = br.y * cg - bi.y * sg, ni1 = br.y * sg + bi.y * cg;
    float nr2 = br.z * cg - bi.z * sg, ni2 = br.z * sg + bi.z * cg;
    float nr3 = br.w * cg - bi.w * sg, ni3 = br.w * sg + bi.w * cg;
    u16* row0 = Bp + (size_t)n * K2;
    u16* row1 = Bp + (size_t)(N_DIM + n) * K2;
    *reinterpret_cast<ushort4*>(row0 + h) =
        make_ushort4(f2bf(nr0), f2bf(nr1), f2bf(nr2), f2bf(nr3));
    *reinterpret_cast<ushort4*>(row0 + 1024 + h) =
        make_ushort4(f2bf(-ni0), f2bf(-ni1), f2bf(-ni2), f2bf(-ni3));
    *reinterpret_cast<ushort4*>(row1 + h) =
        make_ushort4(f2bf(ni0), f2bf(ni1), f2bf(ni2), f2bf(ni3));
    *reinterpret_cast<ushort4*>(row1 + 1024 + h) =
        make_ushort4(f2bf(nr0), f2bf(nr1), f2bf(nr2), f2bf(nr3));
}

// ---------------------------------------------------------------------------
// C pack -> Cp bf16 [H][2N]: row h = [ C_r[h][:] | -C_i[h][:] ]
// ---------------------------------------------------------------------------
__global__ void pack_C(const float* __restrict__ Cr, const float* __restrict__ Ci,
                       u16* __restrict__ Cp) {
    size_t t = (size_t)blockIdx.x * 256 + threadIdx.x;
    size_t base = t * 4;                      // over H*N
    int h = (int)(base >> 10);
    int n = (int)(base & 1023);
    float4 cr = *reinterpret_cast<const float4*>(Cr + base);
    float4 ci = *reinterpret_cast<const float4*>(Ci + base);
    u16* row = Cp + (size_t)h * K2;
    *reinterpret_cast<ushort4*>(row + n) =
        make_ushort4(f2bf(cr.x), f2bf(cr.y), f2bf(cr.z), f2bf(cr.w));
    *reinterpret_cast<ushort4*>(row + 1024 + n) =
        make_ushort4(f2bf(-ci.x), f2bf(-ci.y), f2bf(-ci.z), f2bf(-ci.w));
}

// ---------------------------------------------------------------------------
// Deep-pipelined 256x256 bf16 MFMA GEMM (T2+T3+T4+T5):
//   BK=64, 8 waves (2M x 4N), per-wave 128x64 output (8x4 frags of 16x16x32).
//   LDS 128 KB: 2 slots x (A 32KB + B 32KB), K-tile double buffer.
//   Barriers never drain vmem: counted s_waitcnt vmcnt(8) at loop top;
//   K-tile t+2 staged into the freed slot AFTER the closing barrier, so its
//   HBM latency overlaps the whole compute of K-tile t+1.
//   Zero-conflict LDS slot swizzle: phys_slot = log_slot ^ ((row>>1)&3),
//   applied both-sides (inverse-permuted global source; linear LDS dest).
// A: [M][lda] bf16 row-major, B: [Nout][lda] bf16 row-major -> Out = A*B^T.
// EPI==0: bf16 store to OutB.
// EPI==2: split-K (bz in grid.z): bz==0 -> P0 = acc ; bz==1 -> OutF = acc+D*Ur
// ---------------------------------------------------------------------------
template <int EPI>
__global__ __launch_bounds__(512, 2) void gemm256(
    const u16* __restrict__ A, const u16* __restrict__ B, int Klen, int lda,
    u16* __restrict__ OutB, float* __restrict__ OutF, int ldo,
    const float* __restrict__ Dv, const float* __restrict__ Ur,
    float* __restrict__ P0) {
    __shared__ __attribute__((aligned(128))) char lds[131072];
    const int tid = threadIdx.x;
    const int l   = tid & 63;
    const int w   = tid >> 6;          // wave 0..7
    const int wm  = w >> 2;            // 0..1  (M half)
    const int wn  = w & 3;             // 0..3  (N quarter)
    const int bz  = (EPI == 2) ? blockIdx.z : 0;
    const long bm = (long)blockIdx.x * 256;
    const long bn = (long)blockIdx.y * 256;

    const u16* Ae = (EPI == 2) ? (A + (size_t)bz * KSEG) : A;
    const u16* Be = (EPI == 2) ? (B + (size_t)bz * KSEG) : B;

    f32x4 acc[8][4];
#pragma unroll
    for (int i = 0; i < 8; ++i)
#pragma unroll
        for (int j = 0; j < 4; ++j) acc[i][j] = (f32x4){0.f, 0.f, 0.f, 0.f};

    // ---- staging geometry -------------------------------------------------
    // One gload instr: 512 thr x 16B = 8KB = 64 rows. thr -> row tid>>3,
    // phys slot tid&7 (linear LDS). Source col-slot = phys ^ ((row>>1)&3)
    // where row bits come from tid>>3 -> ((tid>>4)&3).
    const int    swzcol   = (((tid & 7) ^ ((tid >> 4) & 3)) << 4);   // bytes
    const size_t astride  = (size_t)64 * lda * 2;                    // 64 rows
    const size_t a_src0   = ((size_t)(bm + (tid >> 3)) * lda) * 2 + swzcol;
    const size_t b_src0   = ((size_t)(bn + (tid >> 3)) * lda) * 2 + swzcol;
    const char*  Agb      = (const char*)Ae;
    const char*  Bgb      = (const char*)Be;
    char* ldsd = lds + tid * 16;

    auto STAGE = [&](int kt, int sl) {
        const size_t kofs = (size_t)kt * 128;          // 64 elems * 2B
        char* la = ldsd + sl * 65536;
        char* lb = la + 32768;
#pragma unroll
        for (int j = 0; j < 4; ++j) {
            gload_lds16(Agb + a_src0 + j * astride + kofs, la + j * 8192);
            gload_lds16(Bgb + b_src0 + j * astride + kofs, lb + j * 8192);
        }
    };

    // ---- fragment-read geometry ------------------------------------------
    const int l15   = l & 15;
    const int lslot = l >> 4;          // 0..3 -> 16B k-slice within 32-k half

    const int nt = Klen / 64;
    STAGE(0, 0);
    STAGE(1, 1);

    for (int t = 0; t < nt; ++t) {
        const int s = t & 1;
        if (t < nt - 1) { asm volatile("s_waitcnt vmcnt(8)" ::: "memory"); }
        else            { asm volatile("s_waitcnt vmcnt(0)" ::: "memory"); }
        __builtin_amdgcn_sched_barrier(0);
        __builtin_amdgcn_s_barrier();       // K-tile t fully resident (all waves)
        __builtin_amdgcn_sched_barrier(0);

        const char* lA = lds + s * 65536;
        const char* lB = lA + 32768;
#pragma unroll
        for (int kk = 0; kk < 2; ++kk) {
            bf16x8 af[8], bg[4];
#pragma unroll
            for (int mi = 0; mi < 8; ++mi) {
                int r  = wm * 128 + mi * 16 + l15;
                int sl = (kk << 2) | ((lslot ^ (r >> 1)) & 3);
                af[mi] = *reinterpret_cast<const bf16x8*>(lA + r * 128 + sl * 16);
            }
#pragma unroll
            for (int ni = 0; ni < 4; ++ni) {
                int r  = wn * 64 + ni * 16 + l15;
                int sl = (kk << 2) | ((lslot ^ (r >> 1)) & 3);
                bg[ni] = *reinterpret_cast<const bf16x8*>(lB + r * 128 + sl * 16);
            }
            __builtin_amdgcn_s_setprio(1);
#pragma unroll
            for (int mi = 0; mi < 8; ++mi)
#pragma unroll
                for (int ni = 0; ni < 4; ++ni)
                    acc[mi][ni] = __builtin_amdgcn_mfma_f32_16x16x32_bf16(
                        af[mi], bg[ni], acc[mi][ni], 0, 0, 0);
            __builtin_amdgcn_s_setprio(0);
        }
        __builtin_amdgcn_sched_barrier(0);
        __builtin_amdgcn_s_barrier();       // all waves done reading slot s
        __builtin_amdgcn_sched_barrier(0);
        if (t + 2 < nt) STAGE(t + 2, s);    // overwrite freed slot; stays in
                                            // flight across next K-tile
    }

    // ---- epilogue: C/D layout col = lane&15, row = (lane>>4)*4 + reg ------
#pragma unroll
    for (int mi = 0; mi < 8; ++mi) {
        const long row0 = bm + wm * 128 + mi * 16 + ((l >> 4) << 2);
#pragma unroll
        for (int ni = 0; ni < 4; ++ni) {
            const long col = bn + wn * 64 + ni * 16 + l15;
            if (EPI == 0) {
#pragma unroll
                for (int r = 0; r < 4; ++r)
                    OutB[(size_t)(row0 + r) * ldo + col] = f2bf(acc[mi][ni][r]);
            } else {
                if (bz == 0) {
#pragma unroll
                    for (int r = 0; r < 4; ++r)
                        P0[(size_t)(row0 + r) * ldo + col] = acc[mi][ni][r];
                } else {
                    const float d = Dv[col];
#pragma unroll
                    for (int r = 0; r < 4; ++r) {
                        size_t o = (size_t)(row0 + r) * ldo + col;
                        OutF[o] = acc[mi][ni][r] + d * Ur[o];
                    }
                }
            }
        }
    }
}

// ---------------------------------------------------------------------------
// Split-K combine: y += P0   (float4)
// ---------------------------------------------------------------------------
__global__ void combine_add(float* __restrict__ y, const float* __restrict__ P0) {
    size_t i = ((size_t)blockIdx.x * 256 + threadIdx.x) * 4;
    float4 a = *reinterpret_cast<const float4*>(y + i);
    float4 b = *reinterpret_cast<const float4*>(P0 + i);
    a.x += b.x; a.y += b.y; a.z += b.z; a.w += b.w;
    *reinterpret_cast<float4*>(y + i) = a;
}

// ---------------------------------------------------------------------------
// Scan pass A: per-(chunk, channel) local scan in fp32 state over bf16 X.
// ---------------------------------------------------------------------------
__global__ void scan_local(u16* __restrict__ X,
                           const float* __restrict__ Lr, const float* __restrict__ Li,
                           float* __restrict__ Acr, float* __restrict__ Aci,
                           float* __restrict__ bcr, float* __restrict__ bci) {
    int n = blockIdx.y * 256 + threadIdx.x;   // 0..1023
    int c = blockIdx.x;
    float lr = Lr[n], li = Li[n];
    float sr = 0.f, si = 0.f, pr = 1.f, pi = 0.f;
    size_t base = (size_t)c * CHUNK * K2 + n;
    for (int j = 0; j < CHUNK; ++j) {
        size_t idx = base + (size_t)j * K2;
        float br = bf2f(X[idx]), bi = bf2f(X[idx + 1024]);
        float nr = lr * sr - li * si + br;
        float ni = lr * si + li * sr + bi;
        sr = nr; si = ni;
        X[idx] = f2bf(sr); X[idx + 1024] = f2bf(si);
        float qr = lr * pr - li * pi;
        float qi = lr * pi + li * pr;
        pr = qr; pi = qi;
    }
    Acr[c * N_DIM + n] = pr; Aci[c * N_DIM + n] = pi;
    bcr[c * N_DIM + n] = sr; bci[c * N_DIM + n] = si;
}

// ---------------------------------------------------------------------------
// Scan pass B: sequential scan over NCHUNK chunk summaries (fp32).
// ---------------------------------------------------------------------------
__global__ void scan_carry(const float* __restrict__ Acr, const float* __restrict__ Aci,
                           const float* __restrict__ bcr, const float* __restrict__ bci,
                           float* __restrict__ car, float* __restrict__ cai) {
    int n = blockIdx.x * 256 + threadIdx.x;
    float sr = 0.f, si = 0.f;
    for (int c = 0; c < NCHUNK; ++c) {
        car[c * N_DIM + n] = sr; cai[c * N_DIM + n] = si;
        float ar = Acr[c * N_DIM + n], ai = Aci[c * N_DIM + n];
        float nr = ar * sr - ai * si + bcr[c * N_DIM + n];
        float ni = ar * si + ai * sr + bci[c * N_DIM + n];
        sr = nr; si = ni;
    }
}

// ---------------------------------------------------------------------------
// Scan pass C: X[c*CHUNK+j] += Lambda^(j+1) * carry_in[c]   (bf16 RMW)
// ---------------------------------------------------------------------------
__global__ void scan_fix(u16* __restrict__ X,
                         const float* __restrict__ Lr, const float* __restrict__ Li,
                         const float* __restrict__ car, const float* __restrict__ cai) {
    int n = blockIdx.y * 256 + threadIdx.x;
    int c = blockIdx.x + 1;
    float lr = Lr[n], li = Li[n];
    float cr = car[c * N_DIM + n], ci = cai[c * N_DIM + n];
    float pr = lr * cr - li * ci;
    float pi = lr * ci + li * cr;
    size_t base = (size_t)c * CHUNK * K2 + n;
    for (int j = 0; j < CHUNK; ++j) {
        size_t idx = base + (size_t)j * K2;
        X[idx]        = f2bf(bf2f(X[idx]) + pr);
        X[idx + 1024] = f2bf(bf2f(X[idx + 1024]) + pi);
        float qr = lr * pr - li * pi;
        float qi = lr * pi + li * pr;
        pr = qr; pi = qi;
    }
}

// ---------------------------------------------------------------------------
// Launch
// ---------------------------------------------------------------------------
extern "C" void kernel_launch(void* const* d_in, const int* in_sizes, int n_in,
                              void* d_out, int out_size, void* d_ws, size_t ws_size,
                              hipStream_t stream) {
    (void)in_sizes; (void)n_in; (void)out_size; (void)ws_size;
    const float* input_real = (const float*)d_in[0];
    const float* input_imag = (const float*)d_in[1];
    const float* nu_log     = (const float*)d_in[2];
    const float* theta_log  = (const float*)d_in[3];
    const float* B_real     = (const float*)d_in[4];
    const float* B_imag     = (const float*)d_in[5];
    const float* C_real     = (const float*)d_in[6];
    const float* C_imag     = (const float*)d_in[7];
    const float* D          = (const float*)d_in[8];
    const float* gamma_log  = (const float*)d_in[9];
    float* y = (float*)d_out;

    // Workspace layout (bytes):
    // [0, 4K)    Lr    [4K, 8K)   Li
    // [8K, ~1.5M)  Acr/Aci/bcr/bci/car/cai (6 x 256KB)
    // [2M, 34M)  A' bf16 [8192][2048]  (dead after gemm1)
    //   [2M, 6M)   Cp aliases A' head  (alive after pack_C)
    //   [6M, 38M)  P0 fp32 [8192][1024] (aliases A' tail + Bp head)
    // [34M, 42M) Bp bf16 [2048][2048]  (dead after gemm1)
    // [42M, 74M) X  bf16 [8192][2048]  (Bu -> x in place)
    char* ws = (char*)d_ws;
    float* Lr  = (float*)(ws);
    float* Li  = (float*)(ws + (4 << 10));
    float* Acr = (float*)(ws + (8 << 10));
    float* Aci = Acr + NCHUNK * N_DIM;
    float* bcr = Aci + NCHUNK * N_DIM;
    float* bci = bcr + NCHUNK * N_DIM;
    float* car = bci + NCHUNK * N_DIM;
    float* cai = car + NCHUNK * N_DIM;
    u16* Ap   = (u16*)(ws + ((size_t)2 << 20));
    u16* Cp   = Ap;                                 // alias: used only after gemm1
    float* P0 = (float*)(ws + ((size_t)6 << 20));   // alias: used only after gemm1
    u16* Bp   = (u16*)(ws + ((size_t)34 << 20));
    u16* X    = (u16*)(ws + ((size_t)42 << 20));

    lru_lambda<<<N_DIM / 256, 256, 0, stream>>>(nu_log, theta_log, Lr, Li);
    pack_u<<<(L_SEQ * H_DIM / 4) / 256, 256, 0, stream>>>(input_real, input_imag, Ap);
    bnorm_pack<<<(N_DIM * H_DIM / 4) / 256, 256, 0, stream>>>(B_real, B_imag, gamma_log, Bp);
    // GEMM1: M=8192, Nout=2048, K=2048 -> grid 32x8 = 256 blocks (1/CU)
    gemm256<0><<<dim3(L_SEQ / 256, K2 / 256), 512, 0, stream>>>(
        Ap, Bp, K2, K2, X, nullptr, K2, nullptr, nullptr, nullptr);
    scan_local<<<dim3(NCHUNK, N_DIM / 256), 256, 0, stream>>>(X, Lr, Li, Acr, Aci, bcr, bci);
    scan_carry<<<N_DIM / 256, 256, 0, stream>>>(Acr, Aci, bcr, bci, car, cai);
    scan_fix<<<dim3(NCHUNK - 1, N_DIM / 256), 256, 0, stream>>>(X, Lr, Li, car, cai);
    pack_C<<<(H_DIM * N_DIM / 4) / 256, 256, 0, stream>>>(C_real, C_imag, Cp);
    // GEMM2 split-K x2: grid 32x4x2 = 256 blocks; bz=0 -> P0, bz=1 -> y (+D*u)
    gemm256<2><<<dim3(L_SEQ / 256, H_DIM / 256, 2), 512, 0, stream>>>(
        X, Cp, KSEG, K2, nullptr, y, H_DIM, D, input_real, P0);
    combine_add<<<(L_SEQ * H_DIM / 4) / 256, 256, 0, stream>>>(y, P0);
}

// Round 5
// 183.614 us; speedup vs baseline: 1.4888x; 1.1323x over previous
//
#include <hip/hip_runtime.h>
#include <math.h>

#define L_SEQ 8192
#define H_DIM 1024
#define N_DIM 1024
#define K2    2048          // packed K = 2*H = 2*N
#define NCHUNK 64
#define CHUNK 128

typedef unsigned short u16;
typedef __attribute__((ext_vector_type(8))) __bf16 bf16x8;
typedef __attribute__((ext_vector_type(4))) float  f32x4;

__device__ __forceinline__ u16 f2bf(float x) {
    unsigned int u = __float_as_uint(x);
    u = (u + 0x7fffu + ((u >> 16) & 1u)) >> 16;   // RNE
    return (u16)u;
}
__device__ __forceinline__ float bf2f(u16 h) {
    return __uint_as_float(((unsigned int)h) << 16);
}

__device__ __forceinline__ void gload_lds16(const void* g, void* s) {
    __builtin_amdgcn_global_load_lds(
        (const __attribute__((address_space(1))) unsigned int*)g,
        (__attribute__((address_space(3))) unsigned int*)s, 16, 0, 0);
}

// ---------------------------------------------------------------------------
// Lambda = exp(-exp(nu_log) + i*exp(theta_log))
// ---------------------------------------------------------------------------
__global__ void lru_lambda(const float* __restrict__ nu_log,
                           const float* __restrict__ theta_log,
                           float* __restrict__ Lr, float* __restrict__ Li) {
    int n = blockIdx.x * 256 + threadIdx.x;
    float nu  = expf(nu_log[n]);
    float th  = expf(theta_log[n]);
    float mag = expf(-nu);
    Lr[n] = mag * cosf(th);
    Li[n] = mag * sinf(th);
}

// ---------------------------------------------------------------------------
// Pack u -> A' bf16 [L][2H]: cols [0,1024)=u_r, [1024,2048)=u_i
// ---------------------------------------------------------------------------
__global__ void pack_u(const float* __restrict__ R, const float* __restrict__ I,
                       u16* __restrict__ A) {
    size_t t = (size_t)blockIdx.x * 256 + threadIdx.x;
    size_t base = t * 4;                      // over L*H
    int lrow = (int)(base >> 10);
    int h    = (int)(base & 1023);
    float4 r  = *reinterpret_cast<const float4*>(R + base);
    float4 im = *reinterpret_cast<const float4*>(I + base);
    u16* p0 = A + ((size_t)lrow << 11) + h;
    *reinterpret_cast<ushort4*>(p0) =
        make_ushort4(f2bf(r.x), f2bf(r.y), f2bf(r.z), f2bf(r.w));
    *reinterpret_cast<ushort4*>(p0 + 1024) =
        make_ushort4(f2bf(im.x), f2bf(im.y), f2bf(im.z), f2bf(im.w));
}

// ---------------------------------------------------------------------------
// B_norm pack -> Bp bf16 [2N][2H]
// ---------------------------------------------------------------------------
__global__ void bnorm_pack(const float* __restrict__ Br, const float* __restrict__ Bi,
                           const float* __restrict__ G, u16* __restrict__ Bp) {
    size_t t = (size_t)blockIdx.x * 256 + threadIdx.x;
    size_t base = t * 4;                      // over N*H
    int n = (int)(base >> 10);
    int h = (int)(base & 1023);
    float g = G[n];
    float sg, cg;
    sincosf(g, &sg, &cg);
    float4 br = *reinterpret_cast<const float4*>(Br + base);
    float4 bi = *reinterpret_cast<const float4*>(Bi + base);
    float nr0 = br.x * cg - bi.x * sg, ni0 = br.x * sg + bi.x * cg;
    float nr1 = br.y * cg - bi.y * sg, ni1 = br.y * sg + bi.y * cg;
    float nr2 = br.z * cg - bi.z * sg, ni2 = br.z * sg + bi.z * cg;
    float nr3 = br.w * cg - bi.w * sg, ni3 = br.w * sg + bi.w * cg;
    u16* row0 = Bp + (size_t)n * K2;
    u16* row1 = Bp + (size_t)(N_DIM + n) * K2;
    *reinterpret_cast<ushort4*>(row0 + h) =
        make_ushort4(f2bf(nr0), f2bf(nr1), f2bf(nr2), f2bf(nr3));
    *reinterpret_cast<ushort4*>(row0 + 1024 + h) =
        make_ushort4(f2bf(-ni0), f2bf(-ni1), f2bf(-ni2), f2bf(-ni3));
    *reinterpret_cast<ushort4*>(row1 + h) =
        make_ushort4(f2bf(ni0), f2bf(ni1), f2bf(ni2), f2bf(ni3));
    *reinterpret_cast<ushort4*>(row1 + 1024 + h) =
        make_ushort4(f2bf(nr0), f2bf(nr1), f2bf(nr2), f2bf(nr3));
}

// ---------------------------------------------------------------------------
// C pack -> Cp bf16 [H][2N]: row h = [ C_r[h][:] | -C_i[h][:] ]
// ---------------------------------------------------------------------------
__global__ void pack_C(const float* __restrict__ Cr, const float* __restrict__ Ci,
                       u16* __restrict__ Cp) {
    size_t t = (size_t)blockIdx.x * 256 + threadIdx.x;
    size_t base = t * 4;                      // over H*N
    int h = (int)(base >> 10);
    int n = (int)(base & 1023);
    float4 cr = *reinterpret_cast<const float4*>(Cr + base);
    float4 ci = *reinterpret_cast<const float4*>(Ci + base);
    u16* row = Cp + (size_t)h * K2;
    *reinterpret_cast<ushort4*>(row + n) =
        make_ushort4(f2bf(cr.x), f2bf(cr.y), f2bf(cr.z), f2bf(cr.w));
    *reinterpret_cast<ushort4*>(row + 1024 + n) =
        make_ushort4(f2bf(-ci.x), f2bf(-ci.y), f2bf(-ci.z), f2bf(-ci.w));
}

// ---------------------------------------------------------------------------
// Deep-pipelined BMx256 bf16 MFMA GEMM (T2+T3+T4+T5):
//   BK=64 (128B LDS rows), 8 waves (2M x 4N), double-buffered K-tiles,
//   counted vmcnt (never 0 in main loop) so HBM latency of K-tile t+2
//   overlaps the whole compute of K-tile t+1.
//   3-bit LDS slot swizzle: phys_slot3 = log_slot3 ^ (row&7) -> each 16-lane
//   ds_read_b128 group spreads over 8 slots = 2 lanes/bank-quad (free).
//   Both-sides rule: linear LDS dest, inverse-permuted global source.
// WMF: A-fragments per wave (8 -> BM=256, 4 -> BM=128).
// A: [M][lda] bf16 row-major, B: [Nout][lda] bf16 row-major -> Out = A*B^T.
// EPI==0: bf16 store to OutB.   EPI==1: OutF = acc + Dv[col]*Ur[row,col].
// ---------------------------------------------------------------------------
template <int EPI, int WMF>
__global__ __launch_bounds__(512, 2) void gemm_pipe(
    const u16* __restrict__ A, const u16* __restrict__ B, int Klen, int lda,
    u16* __restrict__ OutB, float* __restrict__ OutF, int ldo,
    const float* __restrict__ Dv, const float* __restrict__ Ur) {
    constexpr int BM     = WMF * 32;          // 256 or 128
    constexpr int BN     = 256;
    constexpr int ABYTES = BM * 128;          // A slot bytes
    constexpr int SLOT   = (BM + BN) * 128;   // A+B slot bytes
    __shared__ __attribute__((aligned(128))) char lds[2 * SLOT];
    const int tid = threadIdx.x;
    const int l   = tid & 63;
    const int w   = tid >> 6;          // wave 0..7
    const int wm  = w >> 2;            // 0..1  (M half)
    const int wn  = w & 3;             // 0..3  (N quarter)
    const long bm = (long)blockIdx.x * BM;
    const long bn = (long)blockIdx.y * BN;

    f32x4 acc[WMF][4];
#pragma unroll
    for (int i = 0; i < WMF; ++i)
#pragma unroll
        for (int j = 0; j < 4; ++j) acc[i][j] = (f32x4){0.f, 0.f, 0.f, 0.f};

    // ---- staging: one gload covers 64 rows (512 thr x 16B). thr -> row
    // tid>>3, phys slot tid&7 (linear LDS). Source slot = phys ^ (row&7).
    const int    swzcol    = (((tid & 7) ^ ((tid >> 3) & 7)) << 4);
    const size_t rowstride = (size_t)lda * 2;
    const size_t a_src0    = (size_t)(bm + (tid >> 3)) * rowstride + swzcol;
    const size_t b_src0    = (size_t)(bn + (tid >> 3)) * rowstride + swzcol;
    const char*  Agb       = (const char*)A;
    const char*  Bgb       = (const char*)B;

    auto STAGE = [&](int kt, int sl) {
        const size_t kofs = (size_t)kt * 128;          // 64 elems * 2B
        char* la = lds + sl * SLOT + tid * 16;
        char* lb = lds + sl * SLOT + ABYTES + tid * 16;
#pragma unroll
        for (int j = 0; j < BM / 64; ++j)
            gload_lds16(Agb + a_src0 + (size_t)j * 64 * rowstride + kofs,
                        la + j * 8192);
#pragma unroll
        for (int j = 0; j < 4; ++j)
            gload_lds16(Bgb + b_src0 + (size_t)j * 64 * rowstride + kofs,
                        lb + j * 8192);
    };

    const int l15   = l & 15;
    const int lslot = l >> 4;          // 16B k-slice within 32-k half

    const int nt = Klen / 64;
    STAGE(0, 0);
    STAGE(1, 1);

    for (int t = 0; t < nt; ++t) {
        const int s = t & 1;
        if (t < nt - 1) {
            // one STAGE ((BM+BN)/64 loads) may remain in flight
            if constexpr (BM == 256) asm volatile("s_waitcnt vmcnt(8)" ::: "memory");
            else                     asm volatile("s_waitcnt vmcnt(6)" ::: "memory");
        } else {
            asm volatile("s_waitcnt vmcnt(0)" ::: "memory");
        }
        __builtin_amdgcn_sched_barrier(0);
        __builtin_amdgcn_s_barrier();       // K-tile t resident for all waves
        __builtin_amdgcn_sched_barrier(0);

        const char* lA = lds + s * SLOT;
        const char* lB = lA + ABYTES;
#pragma unroll
        for (int kk = 0; kk < 2; ++kk) {
            bf16x8 af[WMF], bg[4];
#pragma unroll
            for (int mi = 0; mi < WMF; ++mi) {
                int r   = wm * (WMF * 16) + mi * 16 + l15;
                int sl3 = ((kk << 2) | lslot) ^ (r & 7);
                af[mi]  = *reinterpret_cast<const bf16x8*>(lA + r * 128 + sl3 * 16);
            }
#pragma unroll
            for (int ni = 0; ni < 4; ++ni) {
                int r   = wn * 64 + ni * 16 + l15;
                int sl3 = ((kk << 2) | lslot) ^ (r & 7);
                bg[ni]  = *reinterpret_cast<const bf16x8*>(lB + r * 128 + sl3 * 16);
            }
            __builtin_amdgcn_s_setprio(1);
#pragma unroll
            for (int mi = 0; mi < WMF; ++mi)
#pragma unroll
                for (int ni = 0; ni < 4; ++ni)
                    acc[mi][ni] = __builtin_amdgcn_mfma_f32_16x16x32_bf16(
                        af[mi], bg[ni], acc[mi][ni], 0, 0, 0);
            __builtin_amdgcn_s_setprio(0);
        }
        __builtin_amdgcn_sched_barrier(0);
        __builtin_amdgcn_s_barrier();       // all waves done reading slot s
        __builtin_amdgcn_sched_barrier(0);
        if (t + 2 < nt) STAGE(t + 2, s);    // stays in flight across K-tile t+1
    }

    // ---- epilogue: C/D layout col = lane&15, row = (lane>>4)*4 + reg ------
#pragma unroll
    for (int mi = 0; mi < WMF; ++mi) {
        const long row0 = bm + wm * (WMF * 16) + mi * 16 + ((l >> 4) << 2);
#pragma unroll
        for (int ni = 0; ni < 4; ++ni) {
            const long col = bn + wn * 64 + ni * 16 + l15;
            if (EPI == 0) {
#pragma unroll
                for (int r = 0; r < 4; ++r)
                    OutB[(size_t)(row0 + r) * ldo + col] = f2bf(acc[mi][ni][r]);
            } else {
                const float d = Dv[col];
#pragma unroll
                for (int r = 0; r < 4; ++r) {
                    size_t o = (size_t)(row0 + r) * ldo + col;
                    OutF[o] = acc[mi][ni][r] + d * Ur[o];
                }
            }
        }
    }
}

// ---------------------------------------------------------------------------
// Scan pass A: per-(chunk, channel) local scan in fp32 state over bf16 X.
// ---------------------------------------------------------------------------
__global__ void scan_local(u16* __restrict__ X,
                           const float* __restrict__ Lr, const float* __restrict__ Li,
                           float* __restrict__ Acr, float* __restrict__ Aci,
                           float* __restrict__ bcr, float* __restrict__ bci) {
    int n = blockIdx.y * 256 + threadIdx.x;   // 0..1023
    int c = blockIdx.x;
    float lr = Lr[n], li = Li[n];
    float sr = 0.f, si = 0.f, pr = 1.f, pi = 0.f;
    size_t base = (size_t)c * CHUNK * K2 + n;
    for (int j = 0; j < CHUNK; ++j) {
        size_t idx = base + (size_t)j * K2;
        float br = bf2f(X[idx]), bi = bf2f(X[idx + 1024]);
        float nr = lr * sr - li * si + br;
        float ni = lr * si + li * sr + bi;
        sr = nr; si = ni;
        X[idx] = f2bf(sr); X[idx + 1024] = f2bf(si);
        float qr = lr * pr - li * pi;
        float qi = lr * pi + li * pr;
        pr = qr; pi = qi;
    }
    Acr[c * N_DIM + n] = pr; Aci[c * N_DIM + n] = pi;
    bcr[c * N_DIM + n] = sr; bci[c * N_DIM + n] = si;
}

// ---------------------------------------------------------------------------
// Scan pass B: sequential scan over NCHUNK chunk summaries (fp32).
// ---------------------------------------------------------------------------
__global__ void scan_carry(const float* __restrict__ Acr, const float* __restrict__ Aci,
                           const float* __restrict__ bcr, const float* __restrict__ bci,
                           float* __restrict__ car, float* __restrict__ cai) {
    int n = blockIdx.x * 256 + threadIdx.x;
    float sr = 0.f, si = 0.f;
    for (int c = 0; c < NCHUNK; ++c) {
        car[c * N_DIM + n] = sr; cai[c * N_DIM + n] = si;
        float ar = Acr[c * N_DIM + n], ai = Aci[c * N_DIM + n];
        float nr = ar * sr - ai * si + bcr[c * N_DIM + n];
        float ni = ar * si + ai * sr + bci[c * N_DIM + n];
        sr = nr; si = ni;
    }
}

// ---------------------------------------------------------------------------
// Scan pass C: X[c*CHUNK+j] += Lambda^(j+1) * carry_in[c]   (bf16 RMW)
// ---------------------------------------------------------------------------
__global__ void scan_fix(u16* __restrict__ X,
                         const float* __restrict__ Lr, const float* __restrict__ Li,
                         const float* __restrict__ car, const float* __restrict__ cai) {
    int n = blockIdx.y * 256 + threadIdx.x;
    int c = blockIdx.x + 1;
    float lr = Lr[n], li = Li[n];
    float cr = car[c * N_DIM + n], ci = cai[c * N_DIM + n];
    float pr = lr * cr - li * ci;
    float pi = lr * ci + li * cr;
    size_t base = (size_t)c * CHUNK * K2 + n;
    for (int j = 0; j < CHUNK; ++j) {
        size_t idx = base + (size_t)j * K2;
        X[idx]        = f2bf(bf2f(X[idx]) + pr);
        X[idx + 1024] = f2bf(bf2f(X[idx + 1024]) + pi);
        float qr = lr * pr - li * pi;
        float qi = lr * pi + li * pr;
        pr = qr; pi = qi;
    }
}

// ---------------------------------------------------------------------------
// Launch
// ---------------------------------------------------------------------------
extern "C" void kernel_launch(void* const* d_in, const int* in_sizes, int n_in,
                              void* d_out, int out_size, void* d_ws, size_t ws_size,
                              hipStream_t stream) {
    (void)in_sizes; (void)n_in; (void)out_size; (void)ws_size;
    const float* input_real = (const float*)d_in[0];
    const float* input_imag = (const float*)d_in[1];
    const float* nu_log     = (const float*)d_in[2];
    const float* theta_log  = (const float*)d_in[3];
    const float* B_real     = (const float*)d_in[4];
    const float* B_imag     = (const float*)d_in[5];
    const float* C_real     = (const float*)d_in[6];
    const float* C_imag     = (const float*)d_in[7];
    const float* D          = (const float*)d_in[8];
    const float* gamma_log  = (const float*)d_in[9];
    float* y = (float*)d_out;

    // Workspace layout (bytes):
    // [0, 4K)    Lr    [4K, 8K)   Li
    // [8K, ~1.5M)  Acr/Aci/bcr/bci/car/cai (6 x 256KB)
    // [2M, 34M)  A' bf16 [8192][2048]  (dead after gemm1)
    //   [2M, 6M)   Cp aliases A' head  (alive after pack_C)
    // [34M, 42M) Bp bf16 [2048][2048]  (dead after gemm1)
    // [42M, 74M) X  bf16 [8192][2048]  (Bu -> x in place)
    char* ws = (char*)d_ws;
    float* Lr  = (float*)(ws);
    float* Li  = (float*)(ws + (4 << 10));
    float* Acr = (float*)(ws + (8 << 10));
    float* Aci = Acr + NCHUNK * N_DIM;
    float* bcr = Aci + NCHUNK * N_DIM;
    float* bci = bcr + NCHUNK * N_DIM;
    float* car = bci + NCHUNK * N_DIM;
    float* cai = car + NCHUNK * N_DIM;
    u16* Ap   = (u16*)(ws + ((size_t)2 << 20));
    u16* Cp   = Ap;                                 // alias: used only after gemm1
    u16* Bp   = (u16*)(ws + ((size_t)34 << 20));
    u16* X    = (u16*)(ws + ((size_t)42 << 20));

    lru_lambda<<<N_DIM / 256, 256, 0, stream>>>(nu_log, theta_log, Lr, Li);
    pack_u<<<(L_SEQ * H_DIM / 4) / 256, 256, 0, stream>>>(input_real, input_imag, Ap);
    bnorm_pack<<<(N_DIM * H_DIM / 4) / 256, 256, 0, stream>>>(B_real, B_imag, gamma_log, Bp);
    // GEMM1: 256x256 tile, grid 32x8 = 256 blocks (1/CU), K=2048
    gemm_pipe<0, 8><<<dim3(L_SEQ / 256, K2 / 256), 512, 0, stream>>>(
        Ap, Bp, K2, K2, X, nullptr, K2, nullptr, nullptr);
    scan_local<<<dim3(NCHUNK, N_DIM / 256), 256, 0, stream>>>(X, Lr, Li, Acr, Aci, bcr, bci);
    scan_carry<<<N_DIM / 256, 256, 0, stream>>>(Acr, Aci, bcr, bci, car, cai);
    scan_fix<<<dim3(NCHUNK - 1, N_DIM / 256), 256, 0, stream>>>(X, Lr, Li, car, cai);
    pack_C<<<(H_DIM * N_DIM / 4) / 256, 256, 0, stream>>>(C_real, C_imag, Cp);
    // GEMM2: 128x256 tile, grid 64x4 = 256 blocks (1/CU), full K=2048,
    // fused D*u_r epilogue, no split-K partials
    gemm_pipe<1, 4><<<dim3(L_SEQ / 128, H_DIM / 256), 512, 0, stream>>>(
        X, Cp, K2, K2, nullptr, y, H_DIM, D, input_real);
}

// Round 6
// 182.430 us; speedup vs baseline: 1.4984x; 1.0065x over previous
//
#include <hip/hip_runtime.h>
#include <math.h>

#define L_SEQ 8192
#define H_DIM 1024
#define N_DIM 1024
#define K2    2048          // packed K = 2*H = 2*N
#define NCHUNK 64
#define CHUNK 128

typedef unsigned short u16;
typedef __attribute__((ext_vector_type(8))) __bf16 bf16x8;
typedef __attribute__((ext_vector_type(4))) float  f32x4;

__device__ __forceinline__ u16 f2bf(float x) {
    unsigned int u = __float_as_uint(x);
    u = (u + 0x7fffu + ((u >> 16) & 1u)) >> 16;   // RNE
    return (u16)u;
}
__device__ __forceinline__ float bf2f(u16 h) {
    return __uint_as_float(((unsigned int)h) << 16);
}

__device__ __forceinline__ void gload_lds16(const void* g, void* s) {
    __builtin_amdgcn_global_load_lds(
        (const __attribute__((address_space(1))) unsigned int*)g,
        (__attribute__((address_space(3))) unsigned int*)s, 16, 0, 0);
}

// ---------------------------------------------------------------------------
// Lambda = exp(-exp(nu_log) + i*exp(theta_log))
// ---------------------------------------------------------------------------
__global__ void lru_lambda(const float* __restrict__ nu_log,
                           const float* __restrict__ theta_log,
                           float* __restrict__ Lr, float* __restrict__ Li) {
    int n = blockIdx.x * 256 + threadIdx.x;
    float nu  = expf(nu_log[n]);
    float th  = expf(theta_log[n]);
    float mag = expf(-nu);
    Lr[n] = mag * cosf(th);
    Li[n] = mag * sinf(th);
}

// ---------------------------------------------------------------------------
// Pack u -> A' bf16 [L][2H]: cols [0,1024)=u_r, [1024,2048)=u_i
// ---------------------------------------------------------------------------
__global__ void pack_u(const float* __restrict__ R, const float* __restrict__ I,
                       u16* __restrict__ A) {
    size_t t = (size_t)blockIdx.x * 256 + threadIdx.x;
    size_t base = t * 4;                      // over L*H
    int lrow = (int)(base >> 10);
    int h    = (int)(base & 1023);
    float4 r  = *reinterpret_cast<const float4*>(R + base);
    float4 im = *reinterpret_cast<const float4*>(I + base);
    u16* p0 = A + ((size_t)lrow << 11) + h;
    *reinterpret_cast<ushort4*>(p0) =
        make_ushort4(f2bf(r.x), f2bf(r.y), f2bf(r.z), f2bf(r.w));
    *reinterpret_cast<ushort4*>(p0 + 1024) =
        make_ushort4(f2bf(im.x), f2bf(im.y), f2bf(im.z), f2bf(im.w));
}

// ---------------------------------------------------------------------------
// B_norm pack -> Bp bf16 [2N][2H]
// ---------------------------------------------------------------------------
__global__ void bnorm_pack(const float* __restrict__ Br, const float* __restrict__ Bi,
                           const float* __restrict__ G, u16* __restrict__ Bp) {
    size_t t = (size_t)blockIdx.x * 256 + threadIdx.x;
    size_t base = t * 4;                      // over N*H
    int n = (int)(base >> 10);
    int h = (int)(base & 1023);
    float g = G[n];
    float sg, cg;
    sincosf(g, &sg, &cg);
    float4 br = *reinterpret_cast<const float4*>(Br + base);
    float4 bi = *reinterpret_cast<const float4*>(Bi + base);
    float nr0 = br.x * cg - bi.x * sg, ni0 = br.x * sg + bi.x * cg;
    float nr1 = br.y * cg - bi.y * sg, ni1 = br.y * sg + bi.y * cg;
    float nr2 = br.z * cg - bi.z * sg, ni2 = br.z * sg + bi.z * cg;
    float nr3 = br.w * cg - bi.w * sg, ni3 = br.w * sg + bi.w * cg;
    u16* row0 = Bp + (size_t)n * K2;
    u16* row1 = Bp + (size_t)(N_DIM + n) * K2;
    *reinterpret_cast<ushort4*>(row0 + h) =
        make_ushort4(f2bf(nr0), f2bf(nr1), f2bf(nr2), f2bf(nr3));
    *reinterpret_cast<ushort4*>(row0 + 1024 + h) =
        make_ushort4(f2bf(-ni0), f2bf(-ni1), f2bf(-ni2), f2bf(-ni3));
    *reinterpret_cast<ushort4*>(row1 + h) =
        make_ushort4(f2bf(ni0), f2bf(ni1), f2bf(ni2), f2bf(ni3));
    *reinterpret_cast<ushort4*>(row1 + 1024 + h) =
        make_ushort4(f2bf(nr0), f2bf(nr1), f2bf(nr2), f2bf(nr3));
}

// ---------------------------------------------------------------------------
// C pack -> Cp bf16 [H][2N]: row h = [ C_r[h][:] | -C_i[h][:] ]
// ---------------------------------------------------------------------------
__global__ void pack_C(const float* __restrict__ Cr, const float* __restrict__ Ci,
                       u16* __restrict__ Cp) {
    size_t t = (size_t)blockIdx.x * 256 + threadIdx.x;
    size_t base = t * 4;                      // over H*N
    int h = (int)(base >> 10);
    int n = (int)(base & 1023);
    float4 cr = *reinterpret_cast<const float4*>(Cr + base);
    float4 ci = *reinterpret_cast<const float4*>(Ci + base);
    u16* row = Cp + (size_t)h * K2;
    *reinterpret_cast<ushort4*>(row + n) =
        make_ushort4(f2bf(cr.x), f2bf(cr.y), f2bf(cr.z), f2bf(cr.w));
    *reinterpret_cast<ushort4*>(row + 1024 + n) =
        make_ushort4(f2bf(-ci.x), f2bf(-ci.y), f2bf(-ci.z), f2bf(-ci.w));
}

// ---------------------------------------------------------------------------
// Deep-pipelined BMx256 bf16 MFMA GEMM, phase-split (T2+T3+T4+T5):
//   BK=64 (128B LDS rows), 8 waves (2M x 4N), double-buffered K-tiles.
//   Each K-tile = 2 sub-phases with double-buffered fragment registers:
//     Phase A: issue kk1 ds_reads || 2x16-MFMA on kk0 regs; lgkm0; barrier.
//     Phase B: STAGE(t+2); counted vmcnt; barrier; issue next tile's kk0
//              reads || 2x16-MFMA on kk1 regs.
//   ds_read data return hides under MFMA issue; vmcnt never drains to 0 in
//   the main loop; setprio(1) around each 16-MFMA cluster (role diversity).
//   3-bit LDS slot swizzle (phys_slot = log_slot ^ (row&7)), both-sides.
// WMF: A-fragments per wave (8 -> BM=256, 4 -> BM=128).
// A: [M][lda] bf16 row-major, B: [Nout][lda] bf16 row-major -> Out = A*B^T.
// EPI==0: bf16 store to OutB.   EPI==1: OutF = acc + Dv[col]*Ur[row,col].
// ---------------------------------------------------------------------------
template <int EPI, int WMF>
__global__ __launch_bounds__(512, 2) void gemm_pipe(
    const u16* __restrict__ A, const u16* __restrict__ B, int Klen, int lda,
    u16* __restrict__ OutB, float* __restrict__ OutF, int ldo,
    const float* __restrict__ Dv, const float* __restrict__ Ur) {
    constexpr int BM     = WMF * 32;          // 256 or 128
    constexpr int BN     = 256;
    constexpr int ABYTES = BM * 128;          // A slot bytes
    constexpr int SLOT   = (BM + BN) * 128;   // A+B slot bytes
    __shared__ __attribute__((aligned(128))) char lds[2 * SLOT];
    const int tid = threadIdx.x;
    const int l   = tid & 63;
    const int w   = tid >> 6;          // wave 0..7
    const int wm  = w >> 2;            // 0..1  (M half)
    const int wn  = w & 3;             // 0..3  (N quarter)
    const long bm = (long)blockIdx.x * BM;
    const long bn = (long)blockIdx.y * BN;

    f32x4 acc[WMF][4];
#pragma unroll
    for (int i = 0; i < WMF; ++i)
#pragma unroll
        for (int j = 0; j < 4; ++j) acc[i][j] = (f32x4){0.f, 0.f, 0.f, 0.f};

    // ---- staging: one gload covers 64 rows (512 thr x 16B). thr -> row
    // tid>>3, phys slot tid&7 (linear LDS). Source slot = phys ^ (row&7).
    const int    swzcol    = (((tid & 7) ^ ((tid >> 3) & 7)) << 4);
    const size_t rowstride = (size_t)lda * 2;
    const size_t a_src0    = (size_t)(bm + (tid >> 3)) * rowstride + swzcol;
    const size_t b_src0    = (size_t)(bn + (tid >> 3)) * rowstride + swzcol;
    const char*  Agb       = (const char*)A;
    const char*  Bgb       = (const char*)B;

    auto STAGE = [&](int kt, int sl) {
        const size_t kofs = (size_t)kt * 128;          // 64 elems * 2B
        char* la = lds + sl * SLOT + tid * 16;
        char* lb = lds + sl * SLOT + ABYTES + tid * 16;
#pragma unroll
        for (int j = 0; j < BM / 64; ++j)
            gload_lds16(Agb + a_src0 + (size_t)j * 64 * rowstride + kofs,
                        la + j * 8192);
#pragma unroll
        for (int j = 0; j < 4; ++j)
            gload_lds16(Bgb + b_src0 + (size_t)j * 64 * rowstride + kofs,
                        lb + j * 8192);
    };

    const int l15   = l & 15;
    const int lslot = l >> 4;          // 16B k-slice within 32-k half

    auto LOADA = [&](bf16x8 (&af)[WMF], const char* lA, int kk) {
#pragma unroll
        for (int mi = 0; mi < WMF; ++mi) {
            int r   = wm * (WMF * 16) + mi * 16 + l15;
            int sl3 = ((kk << 2) | lslot) ^ (r & 7);
            af[mi]  = *reinterpret_cast<const bf16x8*>(lA + r * 128 + sl3 * 16);
        }
    };
    auto LOADB = [&](bf16x8 (&bg)[4], const char* lB, int kk) {
#pragma unroll
        for (int ni = 0; ni < 4; ++ni) {
            int r   = wn * 64 + ni * 16 + l15;
            int sl3 = ((kk << 2) | lslot) ^ (r & 7);
            bg[ni]  = *reinterpret_cast<const bf16x8*>(lB + r * 128 + sl3 * 16);
        }
    };
    auto MM = [&](bf16x8 (&af)[WMF], bf16x8 (&bg)[4], int nlo) {
        __builtin_amdgcn_s_setprio(1);
#pragma unroll
        for (int mi = 0; mi < WMF; ++mi)
#pragma unroll
            for (int nj = 0; nj < 2; ++nj)
                acc[mi][nlo + nj] = __builtin_amdgcn_mfma_f32_16x16x32_bf16(
                    af[mi], bg[nlo + nj], acc[mi][nlo + nj], 0, 0, 0);
        __builtin_amdgcn_s_setprio(0);
    };

    const int nt = Klen / 64;
    STAGE(0, 0);
    STAGE(1, 1);
    if constexpr (BM == 256) asm volatile("s_waitcnt vmcnt(8)" ::: "memory");
    else                     asm volatile("s_waitcnt vmcnt(6)" ::: "memory");
    __builtin_amdgcn_sched_barrier(0);
    __builtin_amdgcn_s_barrier();          // K-tile 0 resident for all waves
    __builtin_amdgcn_sched_barrier(0);

    bf16x8 afX[WMF], afY[WMF], bgX[4], bgY[4];
    LOADA(afX, lds, 0);
    LOADB(bgX, lds + ABYTES, 0);

    for (int t = 0; t < nt; ++t) {
        const int s = t & 1;
        const char* lA = lds + s * SLOT;
        const char* lB = lA + ABYTES;
        // ---- phase A: issue kk1 reads, MFMA kk0 ---------------------------
        LOADA(afY, lA, 1);
        LOADB(bgY, lB, 1);
        MM(afX, bgX, 0);
        MM(afX, bgX, 2);
        asm volatile("s_waitcnt lgkmcnt(0)" ::: "memory");
        __builtin_amdgcn_sched_barrier(0);
        __builtin_amdgcn_s_barrier();      // all waves done reading slot s
        __builtin_amdgcn_sched_barrier(0);
        // ---- phase B: stage t+2, ensure t+1, next-tile kk0 reads, MFMA kk1
        if (t + 2 < nt) {
            STAGE(t + 2, s);               // overwrite freed slot, stays in
                                           // flight across next K-tile
            if constexpr (BM == 256) asm volatile("s_waitcnt vmcnt(8)" ::: "memory");
            else                     asm volatile("s_waitcnt vmcnt(6)" ::: "memory");
        } else if (t + 1 < nt) {
            asm volatile("s_waitcnt vmcnt(0)" ::: "memory");
        }
        if (t + 1 < nt) {
            __builtin_amdgcn_sched_barrier(0);
            __builtin_amdgcn_s_barrier();  // K-tile t+1 resident for all waves
            __builtin_amdgcn_sched_barrier(0);
            const char* lA2 = lds + (s ^ 1) * SLOT;
            const char* lB2 = lA2 + ABYTES;
            LOADA(afX, lA2, 0);
            LOADB(bgX, lB2, 0);
        }
        MM(afY, bgY, 0);
        MM(afY, bgY, 2);
    }

    // ---- epilogue: C/D layout col = lane&15, row = (lane>>4)*4 + reg ------
#pragma unroll
    for (int mi = 0; mi < WMF; ++mi) {
        const long row0 = bm + wm * (WMF * 16) + mi * 16 + ((l >> 4) << 2);
#pragma unroll
        for (int ni = 0; ni < 4; ++ni) {
            const long col = bn + wn * 64 + ni * 16 + l15;
            if (EPI == 0) {
#pragma unroll
                for (int r = 0; r < 4; ++r)
                    OutB[(size_t)(row0 + r) * ldo + col] = f2bf(acc[mi][ni][r]);
            } else {
                const float d = Dv[col];
#pragma unroll
                for (int r = 0; r < 4; ++r) {
                    size_t o = (size_t)(row0 + r) * ldo + col;
                    OutF[o] = acc[mi][ni][r] + d * Ur[o];
                }
            }
        }
    }
}

// ---------------------------------------------------------------------------
// Scan pass A: per-(chunk, channel) local scan in fp32 state over bf16 X.
// ---------------------------------------------------------------------------
__global__ void scan_local(u16* __restrict__ X,
                           const float* __restrict__ Lr, const float* __restrict__ Li,
                           float* __restrict__ Acr, float* __restrict__ Aci,
                           float* __restrict__ bcr, float* __restrict__ bci) {
    int n = blockIdx.y * 256 + threadIdx.x;   // 0..1023
    int c = blockIdx.x;
    float lr = Lr[n], li = Li[n];
    float sr = 0.f, si = 0.f, pr = 1.f, pi = 0.f;
    size_t base = (size_t)c * CHUNK * K2 + n;
    for (int j = 0; j < CHUNK; ++j) {
        size_t idx = base + (size_t)j * K2;
        float br = bf2f(X[idx]), bi = bf2f(X[idx + 1024]);
        float nr = lr * sr - li * si + br;
        float ni = lr * si + li * sr + bi;
        sr = nr; si = ni;
        X[idx] = f2bf(sr); X[idx + 1024] = f2bf(si);
        float qr = lr * pr - li * pi;
        float qi = lr * pi + li * pr;
        pr = qr; pi = qi;
    }
    Acr[c * N_DIM + n] = pr; Aci[c * N_DIM + n] = pi;
    bcr[c * N_DIM + n] = sr; bci[c * N_DIM + n] = si;
}

// ---------------------------------------------------------------------------
// Scan pass B: sequential scan over NCHUNK chunk summaries (fp32).
// ---------------------------------------------------------------------------
__global__ void scan_carry(const float* __restrict__ Acr, const float* __restrict__ Aci,
                           const float* __restrict__ bcr, const float* __restrict__ bci,
                           float* __restrict__ car, float* __restrict__ cai) {
    int n = blockIdx.x * 256 + threadIdx.x;
    float sr = 0.f, si = 0.f;
    for (int c = 0; c < NCHUNK; ++c) {
        car[c * N_DIM + n] = sr; cai[c * N_DIM + n] = si;
        float ar = Acr[c * N_DIM + n], ai = Aci[c * N_DIM + n];
        float nr = ar * sr - ai * si + bcr[c * N_DIM + n];
        float ni = ar * si + ai * sr + bci[c * N_DIM + n];
        sr = nr; si = ni;
    }
}

// ---------------------------------------------------------------------------
// Scan pass C: X[c*CHUNK+j] += Lambda^(j+1) * carry_in[c]   (bf16 RMW)
// ---------------------------------------------------------------------------
__global__ void scan_fix(u16* __restrict__ X,
                         const float* __restrict__ Lr, const float* __restrict__ Li,
                         const float* __restrict__ car, const float* __restrict__ cai) {
    int n = blockIdx.y * 256 + threadIdx.x;
    int c = blockIdx.x + 1;
    float lr = Lr[n], li = Li[n];
    float cr = car[c * N_DIM + n], ci = cai[c * N_DIM + n];
    float pr = lr * cr - li * ci;
    float pi = lr * ci + li * cr;
    size_t base = (size_t)c * CHUNK * K2 + n;
    for (int j = 0; j < CHUNK; ++j) {
        size_t idx = base + (size_t)j * K2;
        X[idx]        = f2bf(bf2f(X[idx]) + pr);
        X[idx + 1024] = f2bf(bf2f(X[idx + 1024]) + pi);
        float qr = lr * pr - li * pi;
        float qi = lr * pi + li * pr;
        pr = qr; pi = qi;
    }
}

// ---------------------------------------------------------------------------
// Launch
// ---------------------------------------------------------------------------
extern "C" void kernel_launch(void* const* d_in, const int* in_sizes, int n_in,
                              void* d_out, int out_size, void* d_ws, size_t ws_size,
                              hipStream_t stream) {
    (void)in_sizes; (void)n_in; (void)out_size; (void)ws_size;
    const float* input_real = (const float*)d_in[0];
    const float* input_imag = (const float*)d_in[1];
    const float* nu_log     = (const float*)d_in[2];
    const float* theta_log  = (const float*)d_in[3];
    const float* B_real     = (const float*)d_in[4];
    const float* B_imag     = (const float*)d_in[5];
    const float* C_real     = (const float*)d_in[6];
    const float* C_imag     = (const float*)d_in[7];
    const float* D          = (const float*)d_in[8];
    const float* gamma_log  = (const float*)d_in[9];
    float* y = (float*)d_out;

    // Workspace layout (bytes):
    // [0, 4K)    Lr    [4K, 8K)   Li
    // [8K, ~1.5M)  Acr/Aci/bcr/bci/car/cai (6 x 256KB)
    // [2M, 34M)  A' bf16 [8192][2048]  (dead after gemm1)
    //   [2M, 6M)   Cp aliases A' head  (alive after pack_C)
    // [34M, 42M) Bp bf16 [2048][2048]  (dead after gemm1)
    // [42M, 74M) X  bf16 [8192][2048]  (Bu -> x in place)
    char* ws = (char*)d_ws;
    float* Lr  = (float*)(ws);
    float* Li  = (float*)(ws + (4 << 10));
    float* Acr = (float*)(ws + (8 << 10));
    float* Aci = Acr + NCHUNK * N_DIM;
    float* bcr = Aci + NCHUNK * N_DIM;
    float* bci = bcr + NCHUNK * N_DIM;
    float* car = bci + NCHUNK * N_DIM;
    float* cai = car + NCHUNK * N_DIM;
    u16* Ap   = (u16*)(ws + ((size_t)2 << 20));
    u16* Cp   = Ap;                                 // alias: used only after gemm1
    u16* Bp   = (u16*)(ws + ((size_t)34 << 20));
    u16* X    = (u16*)(ws + ((size_t)42 << 20));

    lru_lambda<<<N_DIM / 256, 256, 0, stream>>>(nu_log, theta_log, Lr, Li);
    pack_u<<<(L_SEQ * H_DIM / 4) / 256, 256, 0, stream>>>(input_real, input_imag, Ap);
    bnorm_pack<<<(N_DIM * H_DIM / 4) / 256, 256, 0, stream>>>(B_real, B_imag, gamma_log, Bp);
    // GEMM1: 256x256 tile, grid 32x8 = 256 blocks (1/CU), K=2048
    gemm_pipe<0, 8><<<dim3(L_SEQ / 256, K2 / 256), 512, 0, stream>>>(
        Ap, Bp, K2, K2, X, nullptr, K2, nullptr, nullptr);
    scan_local<<<dim3(NCHUNK, N_DIM / 256), 256, 0, stream>>>(X, Lr, Li, Acr, Aci, bcr, bci);
    scan_carry<<<N_DIM / 256, 256, 0, stream>>>(Acr, Aci, bcr, bci, car, cai);
    scan_fix<<<dim3(NCHUNK - 1, N_DIM / 256), 256, 0, stream>>>(X, Lr, Li, car, cai);
    pack_C<<<(H_DIM * N_DIM / 4) / 256, 256, 0, stream>>>(C_real, C_imag, Cp);
    // GEMM2: 128x256 tile, grid 64x4 = 256 blocks (1/CU), full K=2048,
    // fused D*u_r epilogue
    gemm_pipe<1, 4><<<dim3(L_SEQ / 128, H_DIM / 256), 512, 0, stream>>>(
        X, Cp, K2, K2, nullptr, y, H_DIM, D, input_real);
}